// Round 8
// baseline (345.850 us; speedup 1.0000x reference)
//
#include <hip/hip_runtime.h>

// Morphological skeleton, 16 x 1024 x 1024 f32.
// skel = sum_{k=0..20} ( e_k - dilate3x3(e_{k+1}) ),  e_0 = x, e_{k+1} = erode3x3(e_k)
// (reduce_window SAME semantics: windows clamp at image borders).
//
// Register-resident vertical pipeline, zero LDS tile. 3 dispatches x G=7 fused
// erosion stages. One wave (64 lanes x float4) owns a 256-col band and sweeps
// RCH+16 rows. Per stage: 2-row register buffer (parity-swapped); erode =
// min3 vertical + DPP wave-shift horizontal; dilate of f_{s+1} reuses stage
// s+1's buffers; terms go into an 8-deep register FIFO shifted once per
// 2-step pair.
//
// Round-12 change vs round 11 (337 us): force v_min3_f32 / v_max3_f32 via
// inline asm. Evidence: R7's real -15% VALU cut (VALUBusy 50->44) moved time
// 0% -- the measured issue rate (~0.27M wave-instr/us at 44% busy) only
// reconciles with the source if each min3f/max3f costs TWO v_min/v_max
// instructions, i.e. hipcc (strict IEEE minnum, no fast-math) is not fusing
// fminf(fminf(a,b),c) -> v_min3_f32. The kernel is ~70% min/max tree nodes
// (vm/en/vx/dn: 16 element-ops per stage); 2->1 per node is a ~35% cut with
// zero structural/register change. Values are always finite (BIG sentinels,
// normal data): v_min3/v_max3 are bit-exact here.
//
// Config: 4-wave WGs, RCH=32, EDGE folding, DPP shifts, LE/RE band
// templating, batched acc shift-by-2 (all carried from round 11).
//
// Correctness invariants (desk-verified):
//  - interior test: topOK min at y0-17 >= 0 iff y0>=32; botOK max at y0+38 <
//    1024 iff y0<=960.
//  - y0 = 32k -> t0 = y0-8 even -> pair/parity mapping of pf/skpf holds.
//  - synthetic erode values at OOB/warm-up rows are >= the true clamped
//    erosion => harmless in min chains; masked to -BIG in dilate maxes via
//    wave-uniform row conditionals (EDGE path).
//  - DPP bound-lane 0-fill lands only in border-masked lanes or unowned halo
//    columns (contamination <= 1 col/stage, absorbed by the 8-col shrink).
//  - band-edge folding: band 0 has no lane with gx+4==W (gx max 252), bands
//    1-3 have neither edge lane, band 4 has no gx==0 lane (gx min 768).
//  - batched acc shift-by-2: step A writes slots 6-s / emits acc[0]; step B
//    writes slots 7-s / emits acc[1]; one acc[j]=acc[j+2] shift per pair;
//    stage 0 ASSIGNS its slot (old occupant emitted 2 steps prior, dead).
//  - halos exactly tight: 8 rows warm-up, 8 cols/side shrink; bands own
//    disjoint column ranges {[0,248),[248,488),[488,728),[728,968),
//    [968,1024)} so the skel read-modify-write never races.

static constexpr int W = 1024, H = 1024, NIMG = 16;
static constexpr int RCH = 32;           // output rows per wave
static constexpr int NSTEP = RCH + 16;   // sweep steps (8 warm-up + 8 drain)
static constexpr int WPB = 4;            // waves per workgroup
static constexpr float BIG = 3.0e38f;

// Single-instruction 3-input min/max (gfx950 VOP3). Finite inputs only --
// bit-identical to fminf(fminf(a,b),c) for non-NaN data. Inline asm because
// strict-IEEE hipcc does not reliably fuse minnum chains to v_min3.
__device__ __forceinline__ float min3f(float a, float b, float c) {
    float d;
    asm("v_min3_f32 %0, %1, %2, %3" : "=v"(d) : "v"(a), "v"(b), "v"(c));
    return d;
}
__device__ __forceinline__ float max3f(float a, float b, float c) {
    float d;
    asm("v_max3_f32 %0, %1, %2, %3" : "=v"(d) : "v"(a), "v"(b), "v"(c));
    return d;
}

// DPP whole-wave shifts (gfx9/CDNA-only modes; VALU pipe, no DS).
// wave_shr:1 = 0x138 -> lane i reads lane i-1 (left neighbor); lane 0 = 0.
// wave_shl:1 = 0x130 -> lane i reads lane i+1 (right neighbor); lane 63 = 0.
__device__ __forceinline__ float dpp_left(float v) {
    return __int_as_float(__builtin_amdgcn_mov_dpp(__float_as_int(v), 0x138, 0xF, 0xF, true));
}
__device__ __forceinline__ float dpp_right(float v) {
    return __int_as_float(__builtin_amdgcn_mov_dpp(__float_as_int(v), 0x130, 0xF, 0xF, true));
}

// SOFF: 0 for the first step of a pair (slots 6-s, emit acc[0]),
//       1 for the second (slots 7-s, emit acc[1]). Also the pf/skpf parity.
template<bool FIRST, bool WRITE_E, bool EDGE, bool LE, bool RE, int SOFF>
__device__ __forceinline__
void pipe_step(int t, int y0, int gx,
               bool leftEdge, bool rightEdge, bool lane_ok,
               const float* __restrict__ in, float* __restrict__ eo,
               float* __restrict__ sk,
               float4 (&OB)[7], float4 (&MB)[7], float4& OD, float4& MD,
               float4 (&acc)[8], float4 (&pf)[2], float4 (&skpf)[2])
{
    constexpr int PFI = SOFF;

    // consume input row t (OOB rows are +BIG: erode identity; interior: always in-image)
    float4 cur;
    if (!EDGE || (unsigned)t < (unsigned)H) cur = pf[PFI];
    else                                    cur = make_float4(BIG, BIG, BIG, BIG);
    // prefetch input row t+2 into the slot just consumed
    {
        const int nr = t + 2;
        if ((!EDGE || (unsigned)nr < (unsigned)H) && nr <= y0 + RCH + 7)
            pf[PFI] = *(const float4*)&in[(size_t)nr * W + gx];
    }

#pragma unroll
    for (int s = 0; s < 7; ++s) {
        // invariant at entry: OB[s] = f_s(t-s-2), MB[s] = f_s(t-s-1),
        // cur = f_s(t-s) (produced this step by the previous stage / load).
        const float4 fOld = OB[s];
        const float4 fMid = MB[s];

        // ---- erode: en = f_{s+1}(t-s-1) ----
        float4 vm;
        vm.x = min3f(fOld.x, fMid.x, cur.x);
        vm.y = min3f(fOld.y, fMid.y, cur.y);
        vm.z = min3f(fOld.z, fMid.z, cur.z);
        vm.w = min3f(fOld.w, fMid.w, cur.w);
        float lft = dpp_left(vm.w);             // lane 0: 0-fill -> invalid col
        float rgt = dpp_right(vm.x);            // lane 63: 0-fill -> invalid col
        if (LE && leftEdge)  lft = BIG;         // true image border clamp
        if (RE && rightEdge) rgt = BIG;
        float4 en;
        en.x = min3f(lft,  vm.x, vm.y);
        en.y = min3f(vm.x, vm.y, vm.z);
        en.z = min3f(vm.y, vm.z, vm.w);
        en.w = min3f(vm.z, vm.w, rgt);

        OB[s] = cur;   // old-role slot receives newest f_s row (parity swap)

        // ---- dilate of f_{s+1} centered at row t-s-2 ----
        // gOld/gMid from stage s+1's buffers, read BEFORE their update in
        // iteration s+1 of this same step.
        float4 gOld, gMid;
        if (s < 6) { gOld = OB[s + 1]; gMid = MB[s + 1]; }  // f_{s+1}(t-s-3), (t-s-2)
        else       { gOld = OD;        gMid = MD;        }
        const bool topOK = !EDGE || ((t - s - 3) >= 0);   // row t-s-3 in-image?
        const bool botOK = !EDGE || ((t - s - 1) < H);    // row t-s-1 in-image?
        float4 vx;
        if (!EDGE) {
            vx.x = max3f(gOld.x, gMid.x, en.x);
            vx.y = max3f(gOld.y, gMid.y, en.y);
            vx.z = max3f(gOld.z, gMid.z, en.z);
            vx.w = max3f(gOld.w, gMid.w, en.w);
        } else {
            float txx = topOK ? gOld.x : -BIG, bxx = botOK ? en.x : -BIG;
            float txy = topOK ? gOld.y : -BIG, bxy = botOK ? en.y : -BIG;
            float txz = topOK ? gOld.z : -BIG, bxz = botOK ? en.z : -BIG;
            float txw = topOK ? gOld.w : -BIG, bxw = botOK ? en.w : -BIG;
            vx.x = max3f(txx, gMid.x, bxx);
            vx.y = max3f(txy, gMid.y, bxy);
            vx.z = max3f(txz, gMid.z, bxz);
            vx.w = max3f(txw, gMid.w, bxw);
        }
        float dl = dpp_left(vx.w);
        float dr = dpp_right(vx.x);
        if (LE && leftEdge)  dl = -BIG;
        if (RE && rightEdge) dr = -BIG;
        float4 dn;
        dn.x = max3f(dl,   vx.x, vx.y);
        dn.y = max3f(vx.x, vx.y, vx.z);
        dn.z = max3f(vx.y, vx.z, vx.w);
        dn.w = max3f(vx.z, vx.w, dr);

        // term_s(t-s-2) = f_s(t-s-2) - dilate(f_{s+1})(t-s-2)
        // slot SOFF+6-s (compile-time). Stage 0 ASSIGNS: first writer of row
        // t-2's slot (previous occupant emitted 2 steps ago, dead).
        constexpr int base = SOFF + 6;
        const int slot = base - s;
        if (s == 0) {
            acc[slot].x = fOld.x - dn.x;
            acc[slot].y = fOld.y - dn.y;
            acc[slot].z = fOld.z - dn.z;
            acc[slot].w = fOld.w - dn.w;
        } else {
            acc[slot].x += fOld.x - dn.x;
            acc[slot].y += fOld.y - dn.y;
            acc[slot].z += fOld.z - dn.z;
            acc[slot].w += fOld.w - dn.w;
        }

        if (s == 6) {
            if (WRITE_E) {
                const int er = t - 7;          // en = f_7(t-7)
                if (er >= y0 && er < y0 + RCH && lane_ok)
                    *(float4*)&eo[(size_t)er * W + gx] = en;
            }
            OD = en;
        }
        cur = en;   // becomes f_{s+1}(t-(s+1)) for the next stage
    }

    // ---- emit completed row t-8 (slot SOFF; stage 6 wrote it this step) ----
    if (t >= y0 + 8) {
        const int r = t - 8;
        float4 v = acc[SOFF];
        if (!FIRST) {
            const float4 o = skpf[PFI];        // skel row t-8, prefetched at step t-2
            v.x += o.x; v.y += o.y; v.z += o.z; v.w += o.w;
        }
        if (lane_ok)
            *(float4*)&sk[(size_t)r * W + gx] = v;
    }

    // ---- prefetch old skel row t-6 AFTER emission (consumed at step t+2,
    //      which shares this step's parity and thus this PFI slot) ----
    if (!FIRST) {
        const int pr = t - 6;
        if (pr >= y0 && pr < y0 + RCH)
            skpf[PFI] = *(const float4*)&sk[(size_t)pr * W + gx];
    }
}

template<bool FIRST, bool WRITE_E, bool EDGE, bool LE, bool RE>
__device__ __forceinline__
void sweep(int y0, int gx,
           bool leftEdge, bool rightEdge, bool lane_ok,
           const float* __restrict__ in, float* __restrict__ eo,
           float* __restrict__ sk)
{
    float4 B0[7], B1[7], D0, D1, acc[8], pf[2], skpf[2];
    const float4 big4 = make_float4(BIG, BIG, BIG, BIG);
    const float4 z4   = make_float4(0.f, 0.f, 0.f, 0.f);
#pragma unroll
    for (int s = 0; s < 7; ++s) { B0[s] = big4; B1[s] = big4; }
    D0 = big4; D1 = big4;
#pragma unroll
    for (int j = 0; j < 8; ++j) acc[j] = z4;   // safety only; stage-0 assigns
    pf[0] = big4; pf[1] = big4; skpf[0] = z4; skpf[1] = z4;

    // prefetch input rows t0, t0+1 (interior: always in-image)
    {
        const int r0 = y0 - 8, r1 = y0 - 7;
        if (!EDGE || r0 >= 0) pf[0] = *(const float4*)&in[(size_t)r0 * W + gx];
        if (!EDGE || r1 >= 0) pf[1] = *(const float4*)&in[(size_t)r1 * W + gx];
    }

    const int t0 = y0 - 8;   // even (y0 multiple of 32) -> pair mapping holds
#pragma unroll 1
    for (int t = t0; t < t0 + NSTEP; t += 2) {
        pipe_step<FIRST, WRITE_E, EDGE, LE, RE, 0>(t,     y0, gx, leftEdge, rightEdge, lane_ok,
                                                   in, eo, sk, B0, B1, D0, D1, acc, pf, skpf);
        pipe_step<FIRST, WRITE_E, EDGE, LE, RE, 1>(t + 1, y0, gx, leftEdge, rightEdge, lane_ok,
                                                   in, eo, sk, B1, B0, D1, D0, acc, pf, skpf);
        // one FIFO shift per pair (rows tA-6..tA-1: slots 2..7 -> 0..5)
#pragma unroll
        for (int j = 0; j < 6; ++j) acc[j] = acc[j + 2];
    }
}

template<bool FIRST, bool WRITE_E>
__global__ __launch_bounds__(WPB * 64)
void skel_pipe(const float* __restrict__ ein, float* __restrict__ eout,
               float* __restrict__ skel)
{
    const int lane = threadIdx.x;          // 64 lanes; threadIdx.y selects the wave
    const int bx = blockIdx.x;             // band 0..4
    const int y0 = (blockIdx.y * WPB + (int)threadIdx.y) * RCH;  // private row chunk
    const int img = blockIdx.z;
    const int x0 = (bx == 4) ? 768 : bx * 240;   // last band starts at 1024-256
    const int gx = x0 + 4 * lane;                // gx max = 768 + 252 = 1020

    const size_t base = (size_t)img * (size_t)(W * H);
    const float* __restrict__ in = ein + base;
    float* __restrict__ eo = eout + base;
    float* __restrict__ sk = skel + base;

    const bool leftEdge  = (gx == 0);
    const bool rightEdge = (gx + 4 == W);
    // disjoint write ownership (bands overlap in compute, never in writes)
    const int own_lo = (bx == 0) ? 0 : ((bx == 4) ? 968 : x0 + 8);
    const int own_hi = (bx == 4) ? W : x0 + 248;
    const bool lane_ok = (gx >= own_lo) && (gx < own_hi);

    // interior chunk iff 32 <= y0 <= 960 (header proof)
    const bool edge_chunk = !(y0 >= 32 && y0 <= H - RCH - 32);

    if (bx == 0) {
        if (edge_chunk) sweep<FIRST, WRITE_E, true,  true,  false>(y0, gx, leftEdge, rightEdge, lane_ok, in, eo, sk);
        else            sweep<FIRST, WRITE_E, false, true,  false>(y0, gx, leftEdge, rightEdge, lane_ok, in, eo, sk);
    } else if (bx == 4) {
        if (edge_chunk) sweep<FIRST, WRITE_E, true,  false, true >(y0, gx, leftEdge, rightEdge, lane_ok, in, eo, sk);
        else            sweep<FIRST, WRITE_E, false, false, true >(y0, gx, leftEdge, rightEdge, lane_ok, in, eo, sk);
    } else {
        if (edge_chunk) sweep<FIRST, WRITE_E, true,  false, false>(y0, gx, leftEdge, rightEdge, lane_ok, in, eo, sk);
        else            sweep<FIRST, WRITE_E, false, false, false>(y0, gx, leftEdge, rightEdge, lane_ok, in, eo, sk);
    }
}

extern "C" void kernel_launch(void* const* d_in, const int* in_sizes, int n_in,
                              void* d_out, int out_size, void* d_ws, size_t ws_size,
                              hipStream_t stream)
{
    const float* x = (const float*)d_in[0];
    float* skel = (float*)d_out;
    const size_t n = (size_t)NIMG * W * H;

    float* e0 = (float*)d_ws;
    float* e1 = e0 + n;

    dim3 grid(5, H / (RCH * WPB), NIMG);
    dim3 block(64, WPB);

    // steps 0-6: x -> e0 ; 7-13: e0 -> e1 ; 14-20: e1 -> (none)
    skel_pipe<true,  true ><<<grid, block, 0, stream>>>(x,  e0, skel);
    skel_pipe<false, true ><<<grid, block, 0, stream>>>(e0, e1, skel);
    skel_pipe<false, false><<<grid, block, 0, stream>>>(e1, e0, skel);
}

// Round 9
// 326.914 us; speedup vs baseline: 1.0579x; 1.0579x over previous
//
#include <hip/hip_runtime.h>

// Morphological skeleton, 16 x 1024 x 1024 f32.
// skel = sum_{k=0..20} ( e_k - dilate3x3(e_{k+1}) ),  e_0 = x, e_{k+1} = erode3x3(e_k)
// (reduce_window SAME semantics: windows clamp at image borders).
//
// Register-resident vertical pipeline, zero LDS tile. 3 dispatches x G=7 fused
// erosion stages. One wave (64 lanes x float4) owns a 256-col band and sweeps
// 48 rows in 24 TWO-ROW steps.
//
// Round-13 change vs round 11/12 (337/346 us): halve the serial recurrence.
// Evidence: time tracks the per-wave dependent chain (R2 +chain VALU -> +38%;
// R5 -DS chain latency -> -10%; R7 -15% off-chain VALU -> 0%; R8 min3-asm ->
// 0/worse). R7's A/B pair steps were NOT independent (B reads buffers A just
// wrote): one 7-stage chain traversal per ROW. New scheme: with stage buffers
// f_s(r-1),f_s(r) and incoming f_s(r+1),f_s(r+2), BOTH f_{s+1}(r) and
// f_{s+1}(r+1) are computable at once -> stage-to-stage dependency paid once
// per 2 rows; per-row critical path HALVES. Unlike R4's failed dual-sweep
// (duplicate state, +92 VGPR), row 2 shares all buffers: ~+12 VGPR.
// Also: skpf folded into the acc ring (slots 6,7 seeded from old skel after
// the shift; stage 0 += for !FIRST, assign for FIRST): -8 VGPR.
//
// Config: 4-wave WGs, RCH=32, EDGE folding, DPP shifts, LE/RE band
// templating, fminf-based min3 (R8 asm reverted), batched shift-by-2.
//
// Correctness invariants (desk-verified):
//  - two-row algebra: stage s buffers = f_s(t-s-2), f_s(t-s-1); incoming
//    cur0,cur1 = f_s(t-s), f_s(t+1-s); en0 = min3(fOld,fMid,cur0) (+horiz),
//    en1 = min3(fMid,cur0,cur1) (+horiz) = f_{s+1}(t-s-1), f_{s+1}(t-s);
//    buffers <- (cur0, cur1): no parity swap. Dilate row t-s-2 from
//    (gOld,gMid,en0), row t-s-1 from (gMid,en0,en1), gOld/gMid = stage s+1
//    buffers pre-update (= f_{s+1}(t-s-3), f_{s+1}(t-s-2)); s=6 uses OD/MD.
//  - acc ring: at step t, slots 0..7 = rows t-8..t-1. Stage s writes rows
//    t-s-2 (slot 6-s) and t-s-1 (slot 7-s); emit reads slots 0,1 (rows t-8,
//    t-7, both >= y0 iff t >= y0+8; last step t = y0+38 emits y0+30, y0+31);
//    shift acc[j]=acc[j+2]; then seed slots 6,7 (rows t, t+1) from old skel
//    (guarded to [y0,y0+RCH)), consumed by stage-0 += at step t+2. Unseeded
//    slots carry garbage only for rows never emitted. Halo-lane seed values
//    may race with neighbor bands' stores but never cross lanes (acc is
//    lane-local; DPP only touches vm/vx) and are masked by lane_ok at emit.
//  - EDGE masks: row0 top (t-s-3)>=0, bottom (t-s-1)<H; row1 top (t-s-2)>=0,
//    bottom (t-s)<H. Interior iff 32 <= y0 <= 960 (dependency cone of row y0
//    reaches rows >= y0-8 = t0, all real and in-image).
//  - e-writes: er0 = t-7 (en0), er1 = t-6 (en1), per-row range guards.
//  - synthetic BIG rows (warm-up/OOB) are erode-identities; their dilate
//    contamination lands only in never-emitted rows (or is masked in EDGE).
//  - DPP bound-lane 0-fill lands only in border-masked lanes or unowned halo
//    columns (contamination <= 1 col/stage, absorbed by the 8-col shrink).
//  - bands own disjoint column ranges {[0,248),[248,488),[488,728),
//    [728,968),[968,1024)}: the skel read-modify-write never races.

static constexpr int W = 1024, H = 1024, NIMG = 16;
static constexpr int RCH = 32;           // output rows per wave
static constexpr int NSTEP = RCH + 16;   // 48 rows swept = 24 two-row steps
static constexpr int WPB = 4;            // waves per workgroup
static constexpr float BIG = 3.0e38f;

__device__ __forceinline__ float min3f(float a, float b, float c) { return fminf(fminf(a, b), c); }
__device__ __forceinline__ float max3f(float a, float b, float c) { return fmaxf(fmaxf(a, b), c); }

// DPP whole-wave shifts (gfx9/CDNA-only modes; VALU pipe, no DS).
// wave_shr:1 = 0x138 -> lane i reads lane i-1 (left neighbor); lane 0 = 0.
// wave_shl:1 = 0x130 -> lane i reads lane i+1 (right neighbor); lane 63 = 0.
__device__ __forceinline__ float dpp_left(float v) {
    return __int_as_float(__builtin_amdgcn_mov_dpp(__float_as_int(v), 0x138, 0xF, 0xF, true));
}
__device__ __forceinline__ float dpp_right(float v) {
    return __int_as_float(__builtin_amdgcn_mov_dpp(__float_as_int(v), 0x130, 0xF, 0xF, true));
}

template<bool FIRST, bool WRITE_E, bool EDGE, bool LE, bool RE>
__device__ __forceinline__
void pipe_step2(int t, int y0, int gx,
                bool leftEdge, bool rightEdge, bool lane_ok,
                const float* __restrict__ in, float* __restrict__ eo,
                float* __restrict__ sk,
                float4 (&OB)[7], float4 (&MB)[7], float4& OD, float4& MD,
                float4 (&acc)[8], float4 (&pf)[2])
{
    // consume input rows t, t+1 (OOB rows +BIG: erode identity)
    float4 cur0, cur1;
    if (!EDGE || (unsigned)t < (unsigned)H)       cur0 = pf[0];
    else                                          cur0 = make_float4(BIG, BIG, BIG, BIG);
    if (!EDGE || (unsigned)(t + 1) < (unsigned)H) cur1 = pf[1];
    else                                          cur1 = make_float4(BIG, BIG, BIG, BIG);
    // prefetch input rows t+2, t+3 (consumed next step)
    {
        const int n0 = t + 2, n1 = t + 3;
        if ((!EDGE || (unsigned)n0 < (unsigned)H) && n0 <= y0 + RCH + 7)
            pf[0] = *(const float4*)&in[(size_t)n0 * W + gx];
        if ((!EDGE || (unsigned)n1 < (unsigned)H) && n1 <= y0 + RCH + 7)
            pf[1] = *(const float4*)&in[(size_t)n1 * W + gx];
    }

#pragma unroll
    for (int s = 0; s < 7; ++s) {
        const float4 fOld = OB[s];   // f_s(t-s-2)
        const float4 fMid = MB[s];   // f_s(t-s-1)

        // ---- erode both rows: en0 = f_{s+1}(t-s-1), en1 = f_{s+1}(t-s) ----
        float4 vm0, vm1;
        vm0.x = min3f(fOld.x, fMid.x, cur0.x);
        vm0.y = min3f(fOld.y, fMid.y, cur0.y);
        vm0.z = min3f(fOld.z, fMid.z, cur0.z);
        vm0.w = min3f(fOld.w, fMid.w, cur0.w);
        vm1.x = min3f(fMid.x, cur0.x, cur1.x);
        vm1.y = min3f(fMid.y, cur0.y, cur1.y);
        vm1.z = min3f(fMid.z, cur0.z, cur1.z);
        vm1.w = min3f(fMid.w, cur0.w, cur1.w);
        float l0 = dpp_left(vm0.w), r0 = dpp_right(vm0.x);
        float l1 = dpp_left(vm1.w), r1 = dpp_right(vm1.x);
        if (LE && leftEdge)  { l0 = BIG; l1 = BIG; }
        if (RE && rightEdge) { r0 = BIG; r1 = BIG; }
        float4 en0, en1;
        en0.x = min3f(l0,    vm0.x, vm0.y);
        en0.y = min3f(vm0.x, vm0.y, vm0.z);
        en0.z = min3f(vm0.y, vm0.z, vm0.w);
        en0.w = min3f(vm0.z, vm0.w, r0);
        en1.x = min3f(l1,    vm1.x, vm1.y);
        en1.y = min3f(vm1.x, vm1.y, vm1.z);
        en1.z = min3f(vm1.y, vm1.z, vm1.w);
        en1.w = min3f(vm1.z, vm1.w, r1);

        // ---- dilate of f_{s+1}: centers t-s-2 (dn0) and t-s-1 (dn1) ----
        float4 gOld, gMid;   // f_{s+1}(t-s-3), f_{s+1}(t-s-2): pre-update
        if (s < 6) { gOld = OB[s + 1]; gMid = MB[s + 1]; }
        else       { gOld = OD;        gMid = MD;        }
        float4 vx0, vx1;
        if (!EDGE) {
            vx0.x = max3f(gOld.x, gMid.x, en0.x);
            vx0.y = max3f(gOld.y, gMid.y, en0.y);
            vx0.z = max3f(gOld.z, gMid.z, en0.z);
            vx0.w = max3f(gOld.w, gMid.w, en0.w);
            vx1.x = max3f(gMid.x, en0.x, en1.x);
            vx1.y = max3f(gMid.y, en0.y, en1.y);
            vx1.z = max3f(gMid.z, en0.z, en1.z);
            vx1.w = max3f(gMid.w, en0.w, en1.w);
        } else {
            const bool topOK0 = (t - s - 3) >= 0, botOK0 = (t - s - 1) < H;
            const bool topOK1 = (t - s - 2) >= 0, botOK1 = (t - s) < H;
            vx0.x = max3f(topOK0 ? gOld.x : -BIG, gMid.x, botOK0 ? en0.x : -BIG);
            vx0.y = max3f(topOK0 ? gOld.y : -BIG, gMid.y, botOK0 ? en0.y : -BIG);
            vx0.z = max3f(topOK0 ? gOld.z : -BIG, gMid.z, botOK0 ? en0.z : -BIG);
            vx0.w = max3f(topOK0 ? gOld.w : -BIG, gMid.w, botOK0 ? en0.w : -BIG);
            vx1.x = max3f(topOK1 ? gMid.x : -BIG, en0.x, botOK1 ? en1.x : -BIG);
            vx1.y = max3f(topOK1 ? gMid.y : -BIG, en0.y, botOK1 ? en1.y : -BIG);
            vx1.z = max3f(topOK1 ? gMid.z : -BIG, en0.z, botOK1 ? en1.z : -BIG);
            vx1.w = max3f(topOK1 ? gMid.w : -BIG, en0.w, botOK1 ? en1.w : -BIG);
        }
        float dl0 = dpp_left(vx0.w), dr0 = dpp_right(vx0.x);
        float dl1 = dpp_left(vx1.w), dr1 = dpp_right(vx1.x);
        if (LE && leftEdge)  { dl0 = -BIG; dl1 = -BIG; }
        if (RE && rightEdge) { dr0 = -BIG; dr1 = -BIG; }
        float4 dn0, dn1;
        dn0.x = max3f(dl0,   vx0.x, vx0.y);
        dn0.y = max3f(vx0.x, vx0.y, vx0.z);
        dn0.z = max3f(vx0.y, vx0.z, vx0.w);
        dn0.w = max3f(vx0.z, vx0.w, dr0);
        dn1.x = max3f(dl1,   vx1.x, vx1.y);
        dn1.y = max3f(vx1.x, vx1.y, vx1.z);
        dn1.z = max3f(vx1.y, vx1.z, vx1.w);
        dn1.w = max3f(vx1.z, vx1.w, dr1);

        // ---- terms: row t-s-2 -> slot 6-s; row t-s-1 -> slot 7-s ----
        if (FIRST && s == 0) {
            // first dispatch: stage 0 is the first writer (assign)
            acc[6].x = fOld.x - dn0.x;  acc[6].y = fOld.y - dn0.y;
            acc[6].z = fOld.z - dn0.z;  acc[6].w = fOld.w - dn0.w;
            acc[7].x = fMid.x - dn1.x;  acc[7].y = fMid.y - dn1.y;
            acc[7].z = fMid.z - dn1.z;  acc[7].w = fMid.w - dn1.w;
        } else {
            // !FIRST: slots 6,7 were seeded with old skel after last shift
            acc[6 - s].x += fOld.x - dn0.x;  acc[6 - s].y += fOld.y - dn0.y;
            acc[6 - s].z += fOld.z - dn0.z;  acc[6 - s].w += fOld.w - dn0.w;
            acc[7 - s].x += fMid.x - dn1.x;  acc[7 - s].y += fMid.y - dn1.y;
            acc[7 - s].z += fMid.z - dn1.z;  acc[7 - s].w += fMid.w - dn1.w;
        }

        // ---- rotate: buffers take the two incoming rows (no parity swap) ----
        OB[s] = cur0;
        MB[s] = cur1;

        if (s == 6) {
            if (WRITE_E) {
                const int er0 = t - 7, er1 = t - 6;   // en0 = f_7(t-7), en1 = f_7(t-6)
                if (er0 >= y0 && er0 < y0 + RCH && lane_ok)
                    *(float4*)&eo[(size_t)er0 * W + gx] = en0;
                if (er1 >= y0 && er1 < y0 + RCH && lane_ok)
                    *(float4*)&eo[(size_t)er1 * W + gx] = en1;
            }
            OD = en0;
            MD = en1;
        }
        cur0 = en0;   // become stage s+1's incoming rows
        cur1 = en1;
    }

    // ---- emit completed rows t-8, t-7 (slots 0,1; stage 6 wrote them) ----
    if (t >= y0 + 8) {
        if (lane_ok) {
            *(float4*)&sk[(size_t)(t - 8) * W + gx] = acc[0];
            *(float4*)&sk[(size_t)(t - 7) * W + gx] = acc[1];
        }
    }
    // one shift per 2-row step
#pragma unroll
    for (int j = 0; j < 6; ++j) acc[j] = acc[j + 2];
    // seed slots 6,7 (rows t, t+1) with OLD skel; stage-0 += consumes at t+2.
    // Unseeded (out-of-range) slots keep garbage: those rows are never emitted.
    if (!FIRST) {
        if (t >= y0 && t < y0 + RCH)
            acc[6] = *(const float4*)&sk[(size_t)t * W + gx];
        if (t + 1 >= y0 && t + 1 < y0 + RCH)
            acc[7] = *(const float4*)&sk[(size_t)(t + 1) * W + gx];
    }
}

template<bool FIRST, bool WRITE_E, bool EDGE, bool LE, bool RE>
__device__ __forceinline__
void sweep(int y0, int gx,
           bool leftEdge, bool rightEdge, bool lane_ok,
           const float* __restrict__ in, float* __restrict__ eo,
           float* __restrict__ sk)
{
    float4 OB[7], MB[7], OD, MD, acc[8], pf[2];
    const float4 big4 = make_float4(BIG, BIG, BIG, BIG);
    const float4 z4   = make_float4(0.f, 0.f, 0.f, 0.f);
#pragma unroll
    for (int s = 0; s < 7; ++s) { OB[s] = big4; MB[s] = big4; }
    OD = big4; MD = big4;
#pragma unroll
    for (int j = 0; j < 8; ++j) acc[j] = z4;   // safety; real init via assign/seed
    pf[0] = big4; pf[1] = big4;

    // prefetch input rows t0, t0+1 (interior: always in-image)
    {
        const int r0 = y0 - 8, r1 = y0 - 7;
        if (!EDGE || r0 >= 0) pf[0] = *(const float4*)&in[(size_t)r0 * W + gx];
        if (!EDGE || r1 >= 0) pf[1] = *(const float4*)&in[(size_t)r1 * W + gx];
    }

    const int t0 = y0 - 8;
#pragma unroll 1
    for (int t = t0; t < t0 + NSTEP; t += 2) {
        pipe_step2<FIRST, WRITE_E, EDGE, LE, RE>(t, y0, gx, leftEdge, rightEdge, lane_ok,
                                                 in, eo, sk, OB, MB, OD, MD, acc, pf);
    }
}

template<bool FIRST, bool WRITE_E>
__global__ __launch_bounds__(WPB * 64)
void skel_pipe(const float* __restrict__ ein, float* __restrict__ eout,
               float* __restrict__ skel)
{
    const int lane = threadIdx.x;          // 64 lanes; threadIdx.y selects the wave
    const int bx = blockIdx.x;             // band 0..4
    const int y0 = (blockIdx.y * WPB + (int)threadIdx.y) * RCH;  // private row chunk
    const int img = blockIdx.z;
    const int x0 = (bx == 4) ? 768 : bx * 240;   // last band starts at 1024-256
    const int gx = x0 + 4 * lane;                // gx max = 768 + 252 = 1020

    const size_t base = (size_t)img * (size_t)(W * H);
    const float* __restrict__ in = ein + base;
    float* __restrict__ eo = eout + base;
    float* __restrict__ sk = skel + base;

    const bool leftEdge  = (gx == 0);
    const bool rightEdge = (gx + 4 == W);
    // disjoint write ownership (bands overlap in compute, never in writes)
    const int own_lo = (bx == 0) ? 0 : ((bx == 4) ? 968 : x0 + 8);
    const int own_hi = (bx == 4) ? W : x0 + 248;
    const bool lane_ok = (gx >= own_lo) && (gx < own_hi);

    // interior chunk iff 32 <= y0 <= 960 (header proof)
    const bool edge_chunk = !(y0 >= 32 && y0 <= H - RCH - 32);

    if (bx == 0) {
        if (edge_chunk) sweep<FIRST, WRITE_E, true,  true,  false>(y0, gx, leftEdge, rightEdge, lane_ok, in, eo, sk);
        else            sweep<FIRST, WRITE_E, false, true,  false>(y0, gx, leftEdge, rightEdge, lane_ok, in, eo, sk);
    } else if (bx == 4) {
        if (edge_chunk) sweep<FIRST, WRITE_E, true,  false, true >(y0, gx, leftEdge, rightEdge, lane_ok, in, eo, sk);
        else            sweep<FIRST, WRITE_E, false, false, true >(y0, gx, leftEdge, rightEdge, lane_ok, in, eo, sk);
    } else {
        if (edge_chunk) sweep<FIRST, WRITE_E, true,  false, false>(y0, gx, leftEdge, rightEdge, lane_ok, in, eo, sk);
        else            sweep<FIRST, WRITE_E, false, false, false>(y0, gx, leftEdge, rightEdge, lane_ok, in, eo, sk);
    }
}

extern "C" void kernel_launch(void* const* d_in, const int* in_sizes, int n_in,
                              void* d_out, int out_size, void* d_ws, size_t ws_size,
                              hipStream_t stream)
{
    const float* x = (const float*)d_in[0];
    float* skel = (float*)d_out;
    const size_t n = (size_t)NIMG * W * H;

    float* e0 = (float*)d_ws;
    float* e1 = e0 + n;

    dim3 grid(5, H / (RCH * WPB), NIMG);
    dim3 block(64, WPB);

    // steps 0-6: x -> e0 ; 7-13: e0 -> e1 ; 14-20: e1 -> (none)
    skel_pipe<true,  true ><<<grid, block, 0, stream>>>(x,  e0, skel);
    skel_pipe<false, true ><<<grid, block, 0, stream>>>(e0, e1, skel);
    skel_pipe<false, false><<<grid, block, 0, stream>>>(e1, e0, skel);
}